// Round 11
// baseline (231.383 us; speedup 1.0000x reference)
//
#include <hip/hip_runtime.h>
#include <hip/hip_bf16.h>

// Problem constants
#define NB 2
#define SEQ 2048
#define HEADS 16
#define HD 64
#define ED 1024

typedef __bf16 bf16x8 __attribute__((ext_vector_type(8)));
typedef float f32x4 __attribute__((ext_vector_type(4)));
typedef unsigned short u16x8 __attribute__((ext_vector_type(8)));
typedef unsigned short u16x4 __attribute__((ext_vector_type(4)));

#if __has_builtin(__builtin_amdgcn_exp2f)
#define EXP2(x) __builtin_amdgcn_exp2f(x)   // raw v_exp_f32 (no denorm guard seq)
#else
#define EXP2(x) __builtin_exp2f(x)
#endif

__device__ __forceinline__ unsigned short f2bf(float f) {
    unsigned u = __builtin_bit_cast(unsigned, f);
    u += 0x7fffu + ((u >> 16) & 1u);   // RNE
    return (unsigned short)(u >> 16);
}

__device__ __forceinline__ bf16x8 cvt8(const float* __restrict__ p) {
    const float4* p4 = (const float4*)p;
    float4 a = p4[0], b = p4[1];
    u16x8 u;
    u[0] = f2bf(a.x); u[1] = f2bf(a.y); u[2] = f2bf(a.z); u[3] = f2bf(a.w);
    u[4] = f2bf(b.x); u[5] = f2bf(b.y); u[6] = f2bf(b.z); u[7] = f2bf(b.w);
    return __builtin_bit_cast(bf16x8, u);
}

__device__ __forceinline__ bf16x8 ldfrag(const void* p) {
    uint4 v = *(const uint4*)p;
    return __builtin_bit_cast(bf16x8, v);
}

__device__ __forceinline__ f32x4 mfma16(bf16x8 a, bf16x8 b, f32x4 c) {
    return __builtin_amdgcn_mfma_f32_16x16x32_bf16(a, b, c, 0, 0, 0);
}

// pack two positive f32 into bf16 pair (round-half-up): 2 adds + v_perm.
// PROVEN path. (r10 post-mortem: cvt_pk was EXONERATED -- r9/r10 failed with
// identical absmax under both packers; the real bug was the V-prefetch
// stride below. Keeping packbf anyway: verified > marginal.)
__device__ __forceinline__ unsigned packbf(float lo, float hi) {
    unsigned a = __builtin_bit_cast(unsigned, hi) + 0x8000u;
    unsigned b = __builtin_bit_cast(unsigned, lo) + 0x8000u;
    return __builtin_amdgcn_perm(a, b, 0x07060302u);   // [hi16(a) : hi16(b)]
}

#define GLOAD_LDS(gp, lp) \
    __builtin_amdgcn_global_load_lds( \
        (const __attribute__((address_space(1))) unsigned int*)(gp), \
        (__attribute__((address_space(3))) unsigned int*)(lp), 16, 0, 0)

// softmax scale folded into Q at projection: (1/sqrt(1024)) * log2(e)
#define QSCALE 0.04508422f

// ---------------- kernel: QKV projections + mask->bits + Wo->bf16 ----------
// v5 grid: 0..3071 proj (heavy). 3072..5119 mask bit-pack (fat blocks,
// 4096 ints each). 5120..6143 Wo convert. Total 6144 WGs.
// Q,K stored [n][h][s][64] bf16 (Q pre-scaled by QSCALE);
// V stored tiled [n][h][s/64][d][64] bf16.
__global__ __launch_bounds__(256) void proj_prep_kernel(
    const float* __restrict__ qin, const float* __restrict__ kin, const float* __restrict__ vin,
    const float* __restrict__ Wq, const float* __restrict__ Wk, const float* __restrict__ Wv,
    unsigned short* __restrict__ Qb, unsigned short* __restrict__ Kb,
    unsigned short* __restrict__ Vt,
    const int* __restrict__ mask, unsigned long long* __restrict__ bits,
    const float* __restrict__ Wo, unsigned short* __restrict__ Wob)
{
    __shared__ __align__(16) char tile[64 * 144];   // 64 rows x 144B (128B data + pad)

    int bid = blockIdx.x;
    if (bid >= 3072) {
        int b2 = bid - 3072;
        if (b2 < 2048) {
            // mask bit-pack: 4096 ints per block, 1024 per wave, 16 ballots
            int lane = threadIdx.x & 63;
            size_t base = (size_t)b2 * 4096 + (size_t)(threadIdx.x >> 6) * 1024;
#pragma unroll
            for (int j = 0; j < 16; ++j) {
                size_t i = base + (size_t)j * 64 + lane;
                unsigned long long bb = __ballot(mask[i] != 0);
                if (lane == 0) bits[i >> 6] = bb;
            }
        } else {
            size_t i = ((size_t)(b2 - 2048) * 256 + threadIdx.x) * 4;
            float4 v = *(const float4*)(Wo + i);
            u16x4 u;
            u[0] = f2bf(v.x); u[1] = f2bf(v.y); u[2] = f2bf(v.z); u[3] = f2bf(v.w);
            *(u16x4*)(Wob + i) = u;
        }
        return;
    }

    int t3  = bid >> 10;
    int rem = bid & 1023;
    int h   = rem >> 6;
    int rt  = rem & 63;
    int wave = threadIdx.x >> 6, lane = threadIdx.x & 63;
    int quad = lane >> 4, l16 = lane & 15;

    const float* in = (t3 == 0) ? qin : ((t3 == 1) ? kin : vin);
    const float* W  = (t3 == 0) ? Wq  : ((t3 == 1) ? Wk  : Wv);

    int r0 = rt * 64 + wave * 16;   // global token row base for this wave

    bf16x8 bf0[4], bf1[4];
#pragma unroll
    for (int sl = 0; sl < 4; ++sl) {
        const float* wrow = W + (sl * 16 + l16) * 64;
        bf0[sl] = cvt8(wrow + quad * 8);
        bf1[sl] = cvt8(wrow + 32 + quad * 8);
    }
    const float* xrow = in + (size_t)(r0 + l16) * ED + h * 64;
    bf16x8 af0 = cvt8(xrow + quad * 8);
    bf16x8 af1 = cvt8(xrow + 32 + quad * 8);

    f32x4 acc[4];
#pragma unroll
    for (int sl = 0; sl < 4; ++sl) {
        f32x4 c = {0.f, 0.f, 0.f, 0.f};
        c = mfma16(af0, bf0[sl], c);
        c = mfma16(af1, bf1[sl], c);
        acc[sl] = c;
    }
    float sc = (t3 == 0) ? QSCALE : 1.0f;

    size_t nh = (size_t)((r0 >> 11) * HEADS + h);   // 64-row tile never straddles n
    int rl = lane >> 3, cl = lane & 7;              // readback row-in-group / 16B slot

    if (t3 != 2) {
        // ---- Q/K: LDS tile [s_local][e], wave-private rows, no barrier -----
#pragma unroll
        for (int r = 0; r < 4; ++r) {
            int srow = wave * 16 + quad * 4 + r;
#pragma unroll
            for (int sl = 0; sl < 4; ++sl)
                *(unsigned short*)(tile + srow * 144 + (sl * 16 + l16) * 2) =
                    f2bf(acc[sl][r] * sc);
        }
        unsigned short* dst = (t3 == 0) ? Qb : Kb;
        int s0 = (r0 & 2047);                        // this wave's first token row
#pragma unroll
        for (int g = 0; g < 2; ++g) {
            int lrow = wave * 16 + g * 8 + rl;
            uint4 v = *(const uint4*)(tile + lrow * 144 + cl * 16);
            *(uint4*)(dst + (nh * SEQ + (s0 & ~15) + g * 8 + rl) * HD + cl * 8) = v;
        }
    } else {
        // ---- V: LDS tile [e][s_local] (transpose), barrier across waves ----
#pragma unroll
        for (int r = 0; r < 4; ++r) {
            int srow = wave * 16 + quad * 4 + r;
#pragma unroll
            for (int sl = 0; sl < 4; ++sl)
                *(unsigned short*)(tile + (sl * 16 + l16) * 144 + srow * 2) =
                    f2bf(acc[sl][r]);
        }
        __syncthreads();
        int s_tile = rt & 31;
#pragma unroll
        for (int g = 0; g < 2; ++g) {
            int erow = wave * 16 + g * 8 + rl;
            uint4 v = *(const uint4*)(tile + erow * 144 + cl * 16);
            *(uint4*)(Vt + ((nh * 32 + s_tile) * 64 + erow) * 64 + cl * 8) = v;
        }
    }
}

// ---------------- kernel: flash attention, full-K, no split ----------------
// v11 = v4 (best passing attn: 68.0us) with the r9/r10 bug FIXED.
// ROOT CAUSE (r10 post-mortem): v8's "revert" kept gV as const char* (from
// v6/v7) but copied v4's ELEMENT-based V-prefetch offset (kbn>>6)*4096.
// One V tile = 64x64 bf16 = 8192 BYTES; on a char* the offset must be *8192.
// v9/v10 staged the wrong half-tile of V every iteration -> absmax 0.207
// identical under both packers (which exonerated cvt_pk).
// Structure (v4): each wave does TWO 16-q blocks (shared K/V frags);
// 128 q/block, grid 512 = 2 blocks/CU, 8 waves/CU. K AND V double-buffered,
// ONE barrier per K-tile, both prefetches right after it.
// LDS: K dbuf 16K + V dbuf 16K + P 4x4K = 49152 B.
// Session state: attn invariant at 68+-3us under barrier count, conflicts,
// LDS traffic/query, occupancy, pipelining, DS offload -> additive-pipes
// floor of this structure (VALU 41% + MFMA 22% + LDS, serialized in-wave).
__global__ __launch_bounds__(256, 2) void attn_kernel(
    const unsigned short* __restrict__ Qb, const unsigned short* __restrict__ Kb,
    const unsigned short* __restrict__ Vt2, const unsigned long long* __restrict__ mb,
    unsigned short* __restrict__ Ab)
{
    // K par0 @0, K par1 @8192, V par0 @16384, V par1 @24576,
    // P @32768 + wave*4096 + g*2048
    __shared__ __align__(16) char smem[32768 + 4 * 4096];

    int tid = threadIdx.x;
    int wave = tid >> 6, lane = tid & 63;
    int quad = lane >> 4, l16 = lane & 15;

    // XCD swizzle: 4 consecutive nh per XCD -> K/V resident in its L2
    int b   = blockIdx.x;
    int xcd = b & 7;
    int j   = b >> 3;             // 0..63
    int nh  = xcd * 4 + (j >> 4);
    int qb  = j & 15;
    int n = nh >> 4, h = nh & 15;
    int q0 = qb * 128 + wave * 16;          // q-block 0; q-block 1 at +64

    size_t headoff = (size_t)nh * SEQ * HD;
    // Q fragments (B-operand), two q-blocks
    bf16x8 qf[2][2];
#pragma unroll
    for (int g = 0; g < 2; ++g) {
        const unsigned short* qrow = Qb + headoff + (size_t)(q0 + g * 64 + l16) * HD;
        qf[g][0] = ldfrag(qrow + quad * 8);
        qf[g][1] = ldfrag(qrow + 32 + quad * 8);
    }

    // staging: per-lane source offset (bytes) with rotation ((slot - row)&7)
    int srow = lane >> 3, sslot = lane & 7;
    int stoff = srow * 128 + (((sslot - srow) & 7) * 16);

    // ds read address registers (bytes, loop-invariant; par base added in loop)
    int rotA = ((quad + l16) & 7) * 16;
    int aKV = l16 * 128 + rotA;            // + kt/sl*2048 ; ^64 high half

    // P tiles: per wave 2 x (16 rows x 128B), XOR swizzle bits 4-6 by (l16&7)
    int pswz = (l16 & 7) << 4;
    char* prow0 = smem + 32768 + wave * 4096 + l16 * 128;
    char* prow1 = prow0 + 2048;
    int pwoff = (quad * 8) ^ pswz;         // write: prowG + (pwoff ^ kt*32)
    int proff = (quad * 16) ^ pswz;        // read:  pb0 @ prowG+proff; pb1 @ ^64

    const unsigned short* gK = Kb + headoff;
    // V base kept as ELEMENT pointer (unsigned short*) like v4, so tile
    // offsets below are in elements: one tile = 4096 elements = 8192 B.
    const unsigned short* gV = Vt2 + (size_t)nh * (32 * 4096);
    const unsigned long long* mbase = mb + (size_t)n * (SEQ * SEQ / 64)
                                         + (size_t)(q0 + l16) * (SEQ / 64);
    // q-block 1 mask rows at +64*(SEQ/64) = +2048 elements

    // all-ones bf16 A-fragment for row sums
    u16x8 ou;
#pragma unroll
    for (int jj = 0; jj < 8; ++jj) ou[jj] = 0x3F80;
    bf16x8 ones = __builtin_bit_cast(bf16x8, ou);

    f32x4 o[2][4] = {};
    f32x4 lacc[2] = {{0,0,0,0},{0,0,0,0}};
    int qsh = quad * 4;

    // ---- prologue: stage K_0, V_0 -> parity 0 ------------------------------
    {
        const char* sK = (const char*)gK + stoff;
        const char* sV = (const char*)gV + stoff;
#pragma unroll
        for (int i2 = 0; i2 < 2; ++i2) {
            int c = wave * 2 + i2;
            GLOAD_LDS(sK + c * 1024, smem + c * 1024);
            GLOAD_LDS(sV + c * 1024, smem + 16384 + c * 1024);
        }
    }
    unsigned long long mnext0 = mbase[0] >> qsh;
    unsigned long long mnext1 = mbase[2048] >> qsh;

    int par = 0;
    for (int kb = 0; kb < SEQ; kb += 64) {
        int kbn = (kb + 64) & (SEQ - 1);   // wrapped next tile (harmless at end)
        // ONE barrier: K_i/V_i visible; last iter's prefetches (full-iter
        // lead) drained by the syncthreads-implied s_waitcnt vmcnt(0)
        __syncthreads();
        // ---- prefetch K_{i+1}, V_{i+1} into parity^1 -----------------------
        {
            const char* sK = (const char*)(gK + (size_t)kbn * 64) + stoff;
            // ELEMENT arithmetic on ushort*: (kbn>>6)*4096 elems = 8192 B/tile
            const char* sV = (const char*)(gV + (size_t)(kbn >> 6) * 4096) + stoff;
            char* dK = smem + (par ^ 1) * 8192;
            char* dV = smem + 16384 + (par ^ 1) * 8192;
#pragma unroll
            for (int i2 = 0; i2 < 2; ++i2) {
                int c = wave * 2 + i2;
                GLOAD_LDS(sK + c * 1024, dK + c * 1024);
                GLOAD_LDS(sV + c * 1024, dV + c * 1024);
            }
        }
        // mask rows for this lane's queries: registered one iteration ahead
        unsigned long long m64_0 = mnext0, m64_1 = mnext1;
        mnext0 = mbase[kbn >> 6] >> qsh;
        mnext1 = mbase[2048 + (kbn >> 6)] >> qsh;

        // ---- K fragments (A-operand) from current buffer, shared by both g -
        const char* kbuf = smem + par * 8192;
        bf16x8 kf[4][2];
#pragma unroll
        for (int kt = 0; kt < 4; ++kt) {
            kf[kt][0] = ldfrag(kbuf + aKV + kt * 2048);
            kf[kt][1] = ldfrag(kbuf + (aKV ^ 64) + kt * 2048);
        }
        // ---- per q-block: S^T = K*Q^T ; mask+exp ; P write -----------------
#pragma unroll
        for (int g = 0; g < 2; ++g) {
            unsigned long long m64 = g ? m64_1 : m64_0;
            char* prow = g ? prow1 : prow0;
            f32x4 c[4];
#pragma unroll
            for (int kt = 0; kt < 4; ++kt) {
                f32x4 cc = {0.f, 0.f, 0.f, 0.f};
                cc = mfma16(kf[kt][0], qf[g][0], cc);
                cc = mfma16(kf[kt][1], qf[g][1], cc);
                c[kt] = cc;   // c[kt][r]: key = kb+kt*16+quad*4+r, q = q0+g*64+l16
            }
            unsigned mlo = (unsigned)m64;
            unsigned mhi = (unsigned)(m64 >> 32);
#pragma unroll
            for (int kt = 0; kt < 4; ++kt) {
                unsigned mw = (kt & 2) ? mhi : mlo;
                int bs = (kt & 1) ? 16 : 0;
                float p0 = ((mw >> (bs + 0)) & 1u) ? EXP2(c[kt][0]) : 0.f;
                float p1 = ((mw >> (bs + 1)) & 1u) ? EXP2(c[kt][1]) : 0.f;
                float p2 = ((mw >> (bs + 2)) & 1u) ? EXP2(c[kt][2]) : 0.f;
                float p3 = ((mw >> (bs + 3)) & 1u) ? EXP2(c[kt][3]) : 0.f;
                uint2 dw = { packbf(p0, p1), packbf(p2, p3) };
                *(uint2*)(prow + (pwoff ^ (kt * 32))) = dw;
            }
        }
        // ---- P^T B-fragments (in-wave write->read ordering via DS pipe) ----
        bf16x8 pb[2][2];
        pb[0][0] = ldfrag(prow0 + proff);
        pb[0][1] = ldfrag(prow0 + (proff ^ 64));
        pb[1][0] = ldfrag(prow1 + proff);
        pb[1][1] = ldfrag(prow1 + (proff ^ 64));
        // row sums on the matrix pipe (quad-uniform result)
        lacc[0] = mfma16(ones, pb[0][0], lacc[0]);
        lacc[0] = mfma16(ones, pb[0][1], lacc[0]);
        lacc[1] = mfma16(ones, pb[1][0], lacc[1]);
        lacc[1] = mfma16(ones, pb[1][1], lacc[1]);
        // ---- O^T = V^T * P^T : V fragment read ONCE, used for both g -------
        const char* vbuf = smem + 16384 + par * 8192;
#pragma unroll
        for (int sl = 0; sl < 4; ++sl) {
            bf16x8 va = ldfrag(vbuf + aKV + sl * 2048);
            bf16x8 vx = ldfrag(vbuf + (aKV ^ 64) + sl * 2048);
            o[0][sl] = mfma16(va, pb[0][0], o[0][sl]);
            o[0][sl] = mfma16(vx, pb[0][1], o[0][sl]);
            o[1][sl] = mfma16(va, pb[1][0], o[1][sl]);
            o[1][sl] = mfma16(vx, pb[1][1], o[1][sl]);
        }
        par ^= 1;
    }

    // ---- epilogue: o[g][sl][r] = O[q=q0+g*64+l16][d=sl*16+quad*4+r] --------
#pragma unroll
    for (int g = 0; g < 2; ++g) {
        float rinv = 1.0f / lacc[g][0];     // row-sum, uniform across quads
        int q = q0 + g * 64 + l16;
        unsigned short* op = Ab + (((size_t)(n * SEQ + q)) * HEADS + h) * HD + qsh;
#pragma unroll
        for (int sl = 0; sl < 4; ++sl) {
            u16x4 u;
            u[0] = f2bf(o[g][sl][0] * rinv);
            u[1] = f2bf(o[g][sl][1] * rinv);
            u[2] = f2bf(o[g][sl][2] * rinv);
            u[3] = f2bf(o[g][sl][3] * rinv);
            *(u16x4*)(op + sl * 16) = u;
        }
    }
}

// ---------------- kernel: out = Ab @ Wo^T + bo -----------------------------
// v3: 128x64 tiles, A+B double-buffered (48 KB), ONE barrier per K-step,
// XCD-affinity block remap (xcd owns rt group for all ct -> L2-resident).
__global__ __launch_bounds__(256) void out_gemm_kernel(
    const unsigned short* __restrict__ Ab, const unsigned short* __restrict__ Wob,
    const float* __restrict__ bo, float* __restrict__ out)
{
    // A par0 @0 (16K), A par1 @16384, B par0 @32768 (8K), B par1 @40960
    __shared__ __align__(16) char lds[49152];

    int tid = threadIdx.x;
    int wave = tid >> 6, lane = tid & 63;
    int quad = lane >> 4, l16 = lane & 15;
    int bidx = blockIdx.x;
    int xcdg = bidx & 7;
    int jg   = bidx >> 3;                 // 0..63
    int rt = xcdg * 4 + (jg & 3);
    int ct = jg >> 2;
    int wr = wave >> 1, wc = wave & 1;

    int srow = lane >> 3, sslot = lane & 7;
    int stoff = srow * 2048 + (((sslot - srow) & 7) * 16);
    const char* gA = (const char*)Ab  + (size_t)rt * 128 * 2048 + stoff;
    const char* gB = (const char*)Wob + (size_t)ct * 64 * 2048 + stoff;

    int aA[4], aB[2];    // in-tile offsets, NO base
#pragma unroll
    for (int i = 0; i < 4; ++i) {
        int rowA = wr * 64 + i * 16 + l16;
        aA[i] = rowA * 128 + (((quad + rowA) & 7) * 16);
    }
#pragma unroll
    for (int sl = 0; sl < 2; ++sl) {
        int rowB = wc * 32 + sl * 16 + l16;
        aB[sl] = rowB * 128 + (((quad + rowB) & 7) * 16);
    }

    // ---- prologue: stage f=0 into parity 0 ---------------------------------
#pragma unroll
    for (int i = 0; i < 4; ++i) {
        int c = wave * 4 + i;                      // A: 16 chunks of 8 rows
        GLOAD_LDS(gA + (size_t)c * 16384, lds + c * 1024);
    }
#pragma unroll
    for (int i = 0; i < 2; ++i) {
        int c = wave * 2 + i;                      // B: 8 chunks
        GLOAD_LDS(gB + (size_t)c * 16384, lds + 32768 + c * 1024);
    }

    f32x4 acc[4][2] = {};
    int par = 0;
    for (int f = 0; f < ED; f += 64) {
        int fn = (f + 64) & (ED - 1);              // wrapped (harmless at end)
        __syncthreads();   // tiles(par) visible; prefetches have full-iter lead
        // ---- prefetch next K-slab into parity^1 ----------------------------
        {
            int pA = (par ^ 1) * 16384;
            int pB = 32768 + (par ^ 1) * 8192;
#pragma unroll
            for (int i = 0; i < 4; ++i) {
                int c = wave * 4 + i;
                GLOAD_LDS(gA + (size_t)c * 16384 + fn * 2, lds + pA + c * 1024);
            }
#pragma unroll
            for (int i = 0; i < 2; ++i) {
                int c = wave * 2 + i;
                GLOAD_LDS(gB + (size_t)c * 16384 + fn * 2, lds + pB + c * 1024);
            }
        }
        int bA = par * 16384;
        int bB = 32768 + par * 8192;
#pragma unroll
        for (int kk = 0; kk < 2; ++kk) {
            int x = kk * 64;
            bf16x8 af[4], bfr[2];
#pragma unroll
            for (int i = 0; i < 4; ++i)    af[i]  = ldfrag(lds + bA + (aA[i] ^ x));
#pragma unroll
            for (int sl = 0; sl < 2; ++sl) bfr[sl] = ldfrag(lds + bB + (aB[sl] ^ x));
#pragma unroll
            for (int i = 0; i < 4; ++i)
#pragma unroll
                for (int sl = 0; sl < 2; ++sl)
                    acc[i][sl] = mfma16(af[i], bfr[sl], acc[i][sl]);
        }
        par ^= 1;
    }

    float bv[2];
#pragma unroll
    for (int sl = 0; sl < 2; ++sl)
        bv[sl] = bo[ct * 64 + wc * 32 + sl * 16 + l16];
#pragma unroll
    for (int i = 0; i < 4; ++i)
#pragma unroll
        for (int r = 0; r < 4; ++r) {
            int row = rt * 128 + wr * 64 + i * 16 + quad * 4 + r;
#pragma unroll
            for (int sl = 0; sl < 2; ++sl) {
                int e = ct * 64 + wc * 32 + sl * 16 + l16;
                out[(size_t)row * ED + e] = acc[i][sl][r] + bv[sl];
            }
        }
}

// ---------------- launcher -------------------------------------------------
extern "C" void kernel_launch(void* const* d_in, const int* in_sizes, int n_in,
                              void* d_out, int out_size, void* d_ws, size_t ws_size,
                              hipStream_t stream)
{
    const float* values = (const float*)d_in[0];
    const float* keys   = (const float*)d_in[1];
    const float* query  = (const float*)d_in[2];
    const int*   mask   = (const int*)d_in[3];
    const float* Wv     = (const float*)d_in[4];
    const float* Wk     = (const float*)d_in[5];
    const float* Wq     = (const float*)d_in[6];
    const float* Wo     = (const float*)d_in[7];
    const float* bo     = (const float*)d_in[8];
    float* out = (float*)d_out;

    char* w = (char*)d_ws;
    unsigned short* Qb  = (unsigned short*)(w);              //  8 MB
    unsigned short* Kb  = (unsigned short*)(w +  8388608);   //  8 MB
    unsigned short* Vt  = (unsigned short*)(w + 16777216);   //  8 MB tiled V
    unsigned short* Ab  = (unsigned short*)(w + 25165824);   //  8 MB
    unsigned long long* Mb = (unsigned long long*)(w + 33554432); // 1 MB
    unsigned short* Wob = (unsigned short*)(w + 34603008);   //  2 MB

    proj_prep_kernel<<<3072 + 2048 + 1024, 256, 0, stream>>>(
        query, keys, values, Wq, Wk, Wv, Qb, Kb, Vt, mask, Mb, Wo, Wob);
    attn_kernel<<<512, 256, 0, stream>>>(Qb, Kb, Vt, Mb, Ab);
    out_gemm_kernel<<<512, 256, 0, stream>>>(Ab, Wob, bo, out);
}

// Round 12
// 231.346 us; speedup vs baseline: 1.0002x; 1.0002x over previous
//
#include <hip/hip_runtime.h>
#include <hip/hip_bf16.h>

// Problem constants
#define NB 2
#define SEQ 2048
#define HEADS 16
#define HD 64
#define ED 1024

typedef __bf16 bf16x8 __attribute__((ext_vector_type(8)));
typedef float f32x4 __attribute__((ext_vector_type(4)));
typedef unsigned short u16x8 __attribute__((ext_vector_type(8)));
typedef unsigned short u16x4 __attribute__((ext_vector_type(4)));

#if __has_builtin(__builtin_amdgcn_exp2f)
#define EXP2(x) __builtin_amdgcn_exp2f(x)   // raw v_exp_f32 (no denorm guard seq)
#else
#define EXP2(x) __builtin_exp2f(x)
#endif

__device__ __forceinline__ unsigned short f2bf(float f) {
    unsigned u = __builtin_bit_cast(unsigned, f);
    u += 0x7fffu + ((u >> 16) & 1u);   // RNE
    return (unsigned short)(u >> 16);
}

__device__ __forceinline__ bf16x8 cvt8(const float* __restrict__ p) {
    const float4* p4 = (const float4*)p;
    float4 a = p4[0], b = p4[1];
    u16x8 u;
    u[0] = f2bf(a.x); u[1] = f2bf(a.y); u[2] = f2bf(a.z); u[3] = f2bf(a.w);
    u[4] = f2bf(b.x); u[5] = f2bf(b.y); u[6] = f2bf(b.z); u[7] = f2bf(b.w);
    return __builtin_bit_cast(bf16x8, u);
}

__device__ __forceinline__ bf16x8 ldfrag(const void* p) {
    uint4 v = *(const uint4*)p;
    return __builtin_bit_cast(bf16x8, v);
}

__device__ __forceinline__ f32x4 mfma16(bf16x8 a, bf16x8 b, f32x4 c) {
    return __builtin_amdgcn_mfma_f32_16x16x32_bf16(a, b, c, 0, 0, 0);
}

// pack two positive f32 into bf16 pair (round-half-up): 2 adds + v_perm.
// PROVEN path (r10: cvt_pk exonerated but staying with verified packer).
__device__ __forceinline__ unsigned packbf(float lo, float hi) {
    unsigned a = __builtin_bit_cast(unsigned, hi) + 0x8000u;
    unsigned b = __builtin_bit_cast(unsigned, lo) + 0x8000u;
    return __builtin_amdgcn_perm(a, b, 0x07060302u);   // [hi16(a) : hi16(b)]
}

#define GLOAD_LDS(gp, lp) \
    __builtin_amdgcn_global_load_lds( \
        (const __attribute__((address_space(1))) unsigned int*)(gp), \
        (__attribute__((address_space(3))) unsigned int*)(lp), 16, 0, 0)

// softmax scale folded into Q at projection: (1/sqrt(1024)) * log2(e)
#define QSCALE 0.04508422f

// ---------------- kernel: QKV projections + mask->bits + Wo->bf16 ----------
// v5 grid: 0..3071 proj (heavy). 3072..5119 mask bit-pack (fat blocks,
// 4096 ints each). 5120..6143 Wo convert. Total 6144 WGs.
// Q,K stored [n][h][s][64] bf16 (Q pre-scaled by QSCALE);
// V stored tiled [n][h][s/64][d][64] bf16.
__global__ __launch_bounds__(256) void proj_prep_kernel(
    const float* __restrict__ qin, const float* __restrict__ kin, const float* __restrict__ vin,
    const float* __restrict__ Wq, const float* __restrict__ Wk, const float* __restrict__ Wv,
    unsigned short* __restrict__ Qb, unsigned short* __restrict__ Kb,
    unsigned short* __restrict__ Vt,
    const int* __restrict__ mask, unsigned long long* __restrict__ bits,
    const float* __restrict__ Wo, unsigned short* __restrict__ Wob)
{
    __shared__ __align__(16) char tile[64 * 144];   // 64 rows x 144B (128B data + pad)

    int bid = blockIdx.x;
    if (bid >= 3072) {
        int b2 = bid - 3072;
        if (b2 < 2048) {
            // mask bit-pack: 4096 ints per block, 1024 per wave, 16 ballots
            int lane = threadIdx.x & 63;
            size_t base = (size_t)b2 * 4096 + (size_t)(threadIdx.x >> 6) * 1024;
#pragma unroll
            for (int j = 0; j < 16; ++j) {
                size_t i = base + (size_t)j * 64 + lane;
                unsigned long long bb = __ballot(mask[i] != 0);
                if (lane == 0) bits[i >> 6] = bb;
            }
        } else {
            size_t i = ((size_t)(b2 - 2048) * 256 + threadIdx.x) * 4;
            float4 v = *(const float4*)(Wo + i);
            u16x4 u;
            u[0] = f2bf(v.x); u[1] = f2bf(v.y); u[2] = f2bf(v.z); u[3] = f2bf(v.w);
            *(u16x4*)(Wob + i) = u;
        }
        return;
    }

    int t3  = bid >> 10;
    int rem = bid & 1023;
    int h   = rem >> 6;
    int rt  = rem & 63;
    int wave = threadIdx.x >> 6, lane = threadIdx.x & 63;
    int quad = lane >> 4, l16 = lane & 15;

    const float* in = (t3 == 0) ? qin : ((t3 == 1) ? kin : vin);
    const float* W  = (t3 == 0) ? Wq  : ((t3 == 1) ? Wk  : Wv);

    int r0 = rt * 64 + wave * 16;   // global token row base for this wave

    bf16x8 bf0[4], bf1[4];
#pragma unroll
    for (int sl = 0; sl < 4; ++sl) {
        const float* wrow = W + (sl * 16 + l16) * 64;
        bf0[sl] = cvt8(wrow + quad * 8);
        bf1[sl] = cvt8(wrow + 32 + quad * 8);
    }
    const float* xrow = in + (size_t)(r0 + l16) * ED + h * 64;
    bf16x8 af0 = cvt8(xrow + quad * 8);
    bf16x8 af1 = cvt8(xrow + 32 + quad * 8);

    f32x4 acc[4];
#pragma unroll
    for (int sl = 0; sl < 4; ++sl) {
        f32x4 c = {0.f, 0.f, 0.f, 0.f};
        c = mfma16(af0, bf0[sl], c);
        c = mfma16(af1, bf1[sl], c);
        acc[sl] = c;
    }
    float sc = (t3 == 0) ? QSCALE : 1.0f;

    size_t nh = (size_t)((r0 >> 11) * HEADS + h);   // 64-row tile never straddles n
    int rl = lane >> 3, cl = lane & 7;              // readback row-in-group / 16B slot

    if (t3 != 2) {
        // ---- Q/K: LDS tile [s_local][e], wave-private rows, no barrier -----
#pragma unroll
        for (int r = 0; r < 4; ++r) {
            int srow = wave * 16 + quad * 4 + r;
#pragma unroll
            for (int sl = 0; sl < 4; ++sl)
                *(unsigned short*)(tile + srow * 144 + (sl * 16 + l16) * 2) =
                    f2bf(acc[sl][r] * sc);
        }
        unsigned short* dst = (t3 == 0) ? Qb : Kb;
        int s0 = (r0 & 2047);                        // this wave's first token row
#pragma unroll
        for (int g = 0; g < 2; ++g) {
            int lrow = wave * 16 + g * 8 + rl;
            uint4 v = *(const uint4*)(tile + lrow * 144 + cl * 16);
            *(uint4*)(dst + (nh * SEQ + (s0 & ~15) + g * 8 + rl) * HD + cl * 8) = v;
        }
    } else {
        // ---- V: LDS tile [e][s_local] (transpose), barrier across waves ----
#pragma unroll
        for (int r = 0; r < 4; ++r) {
            int srow = wave * 16 + quad * 4 + r;
#pragma unroll
            for (int sl = 0; sl < 4; ++sl)
                *(unsigned short*)(tile + (sl * 16 + l16) * 144 + srow * 2) =
                    f2bf(acc[sl][r]);
        }
        __syncthreads();
        int s_tile = rt & 31;
#pragma unroll
        for (int g = 0; g < 2; ++g) {
            int erow = wave * 16 + g * 8 + rl;
            uint4 v = *(const uint4*)(tile + erow * 144 + cl * 16);
            *(uint4*)(Vt + ((nh * 32 + s_tile) * 64 + erow) * 64 + cl * 8) = v;
        }
    }
}

// ---------------- kernel: flash attention, full-K, no split ----------------
// v12 = v11 (passing, 69.4us) + s_setprio(1) around the two MFMA clusters
// ONLY. Purpose: isolate the setprio lever that r7 confounded with the
// register-K pipeline (which regressed). m191 precedent: setprio-alone
// +4-7% on attn when co-resident waves sit at different phases -- v11 has
// 2 independent blocks/CU whose barrier domains drift freely. Zero
// correctness risk (pure scheduler hint).
// Structure (v4/v11): each wave does TWO 16-q blocks (shared K/V frags);
// 128 q/block, grid 512 = 2 blocks/CU, 8 waves/CU. K AND V double-buffered,
// ONE barrier per K-tile, both prefetches right after it.
// LDS: K dbuf 16K + V dbuf 16K + P 4x4K = 49152 B.
__global__ __launch_bounds__(256, 2) void attn_kernel(
    const unsigned short* __restrict__ Qb, const unsigned short* __restrict__ Kb,
    const unsigned short* __restrict__ Vt2, const unsigned long long* __restrict__ mb,
    unsigned short* __restrict__ Ab)
{
    // K par0 @0, K par1 @8192, V par0 @16384, V par1 @24576,
    // P @32768 + wave*4096 + g*2048
    __shared__ __align__(16) char smem[32768 + 4 * 4096];

    int tid = threadIdx.x;
    int wave = tid >> 6, lane = tid & 63;
    int quad = lane >> 4, l16 = lane & 15;

    // XCD swizzle: 4 consecutive nh per XCD -> K/V resident in its L2
    int b   = blockIdx.x;
    int xcd = b & 7;
    int j   = b >> 3;             // 0..63
    int nh  = xcd * 4 + (j >> 4);
    int qb  = j & 15;
    int n = nh >> 4, h = nh & 15;
    int q0 = qb * 128 + wave * 16;          // q-block 0; q-block 1 at +64

    size_t headoff = (size_t)nh * SEQ * HD;
    // Q fragments (B-operand), two q-blocks
    bf16x8 qf[2][2];
#pragma unroll
    for (int g = 0; g < 2; ++g) {
        const unsigned short* qrow = Qb + headoff + (size_t)(q0 + g * 64 + l16) * HD;
        qf[g][0] = ldfrag(qrow + quad * 8);
        qf[g][1] = ldfrag(qrow + 32 + quad * 8);
    }

    // staging: per-lane source offset (bytes) with rotation ((slot - row)&7)
    int srow = lane >> 3, sslot = lane & 7;
    int stoff = srow * 128 + (((sslot - srow) & 7) * 16);

    // ds read address registers (bytes, loop-invariant; par base added in loop)
    int rotA = ((quad + l16) & 7) * 16;
    int aKV = l16 * 128 + rotA;            // + kt/sl*2048 ; ^64 high half

    // P tiles: per wave 2 x (16 rows x 128B), XOR swizzle bits 4-6 by (l16&7)
    int pswz = (l16 & 7) << 4;
    char* prow0 = smem + 32768 + wave * 4096 + l16 * 128;
    char* prow1 = prow0 + 2048;
    int pwoff = (quad * 8) ^ pswz;         // write: prowG + (pwoff ^ kt*32)
    int proff = (quad * 16) ^ pswz;        // read:  pb0 @ prowG+proff; pb1 @ ^64

    const unsigned short* gK = Kb + headoff;
    // V base kept as ELEMENT pointer (unsigned short*): one tile = 4096
    // elements = 8192 bytes (r10 root cause -- keep element arithmetic).
    const unsigned short* gV = Vt2 + (size_t)nh * (32 * 4096);
    const unsigned long long* mbase = mb + (size_t)n * (SEQ * SEQ / 64)
                                         + (size_t)(q0 + l16) * (SEQ / 64);
    // q-block 1 mask rows at +64*(SEQ/64) = +2048 elements

    // all-ones bf16 A-fragment for row sums
    u16x8 ou;
#pragma unroll
    for (int jj = 0; jj < 8; ++jj) ou[jj] = 0x3F80;
    bf16x8 ones = __builtin_bit_cast(bf16x8, ou);

    f32x4 o[2][4] = {};
    f32x4 lacc[2] = {{0,0,0,0},{0,0,0,0}};
    int qsh = quad * 4;

    // ---- prologue: stage K_0, V_0 -> parity 0 ------------------------------
    {
        const char* sK = (const char*)gK + stoff;
        const char* sV = (const char*)gV + stoff;
#pragma unroll
        for (int i2 = 0; i2 < 2; ++i2) {
            int c = wave * 2 + i2;
            GLOAD_LDS(sK + c * 1024, smem + c * 1024);
            GLOAD_LDS(sV + c * 1024, smem + 16384 + c * 1024);
        }
    }
    unsigned long long mnext0 = mbase[0] >> qsh;
    unsigned long long mnext1 = mbase[2048] >> qsh;

    int par = 0;
    for (int kb = 0; kb < SEQ; kb += 64) {
        int kbn = (kb + 64) & (SEQ - 1);   // wrapped next tile (harmless at end)
        // ONE barrier: K_i/V_i visible; last iter's prefetches (full-iter
        // lead) drained by the syncthreads-implied s_waitcnt vmcnt(0)
        __syncthreads();
        // ---- prefetch K_{i+1}, V_{i+1} into parity^1 -----------------------
        {
            const char* sK = (const char*)(gK + (size_t)kbn * 64) + stoff;
            // ELEMENT arithmetic on ushort*: (kbn>>6)*4096 elems = 8192 B/tile
            const char* sV = (const char*)(gV + (size_t)(kbn >> 6) * 4096) + stoff;
            char* dK = smem + (par ^ 1) * 8192;
            char* dV = smem + 16384 + (par ^ 1) * 8192;
#pragma unroll
            for (int i2 = 0; i2 < 2; ++i2) {
                int c = wave * 2 + i2;
                GLOAD_LDS(sK + c * 1024, dK + c * 1024);
                GLOAD_LDS(sV + c * 1024, dV + c * 1024);
            }
        }
        // mask rows for this lane's queries: registered one iteration ahead
        unsigned long long m64_0 = mnext0, m64_1 = mnext1;
        mnext0 = mbase[kbn >> 6] >> qsh;
        mnext1 = mbase[2048 + (kbn >> 6)] >> qsh;

        // ---- K fragments (A-operand) from current buffer, shared by both g -
        const char* kbuf = smem + par * 8192;
        bf16x8 kf[4][2];
#pragma unroll
        for (int kt = 0; kt < 4; ++kt) {
            kf[kt][0] = ldfrag(kbuf + aKV + kt * 2048);
            kf[kt][1] = ldfrag(kbuf + (aKV ^ 64) + kt * 2048);
        }
        // ---- per q-block: S^T = K*Q^T ; mask+exp ; P write -----------------
#pragma unroll
        for (int g = 0; g < 2; ++g) {
            unsigned long long m64 = g ? m64_1 : m64_0;
            char* prow = g ? prow1 : prow0;
            f32x4 c[4];
            __builtin_amdgcn_s_setprio(1);   // QK MFMA cluster (T5)
#pragma unroll
            for (int kt = 0; kt < 4; ++kt) {
                f32x4 cc = {0.f, 0.f, 0.f, 0.f};
                cc = mfma16(kf[kt][0], qf[g][0], cc);
                cc = mfma16(kf[kt][1], qf[g][1], cc);
                c[kt] = cc;   // c[kt][r]: key = kb+kt*16+quad*4+r, q = q0+g*64+l16
            }
            __builtin_amdgcn_s_setprio(0);
            unsigned mlo = (unsigned)m64;
            unsigned mhi = (unsigned)(m64 >> 32);
#pragma unroll
            for (int kt = 0; kt < 4; ++kt) {
                unsigned mw = (kt & 2) ? mhi : mlo;
                int bs = (kt & 1) ? 16 : 0;
                float p0 = ((mw >> (bs + 0)) & 1u) ? EXP2(c[kt][0]) : 0.f;
                float p1 = ((mw >> (bs + 1)) & 1u) ? EXP2(c[kt][1]) : 0.f;
                float p2 = ((mw >> (bs + 2)) & 1u) ? EXP2(c[kt][2]) : 0.f;
                float p3 = ((mw >> (bs + 3)) & 1u) ? EXP2(c[kt][3]) : 0.f;
                uint2 dw = { packbf(p0, p1), packbf(p2, p3) };
                *(uint2*)(prow + (pwoff ^ (kt * 32))) = dw;
            }
        }
        // ---- P^T B-fragments (in-wave write->read ordering via DS pipe) ----
        bf16x8 pb[2][2];
        pb[0][0] = ldfrag(prow0 + proff);
        pb[0][1] = ldfrag(prow0 + (proff ^ 64));
        pb[1][0] = ldfrag(prow1 + proff);
        pb[1][1] = ldfrag(prow1 + (proff ^ 64));
        // rowsum + PV MFMA cluster (T5)
        __builtin_amdgcn_s_setprio(1);
        // row sums on the matrix pipe (quad-uniform result)
        lacc[0] = mfma16(ones, pb[0][0], lacc[0]);
        lacc[0] = mfma16(ones, pb[0][1], lacc[0]);
        lacc[1] = mfma16(ones, pb[1][0], lacc[1]);
        lacc[1] = mfma16(ones, pb[1][1], lacc[1]);
        // ---- O^T = V^T * P^T : V fragment read ONCE, used for both g -------
        const char* vbuf = smem + 16384 + par * 8192;
#pragma unroll
        for (int sl = 0; sl < 4; ++sl) {
            bf16x8 va = ldfrag(vbuf + aKV + sl * 2048);
            bf16x8 vx = ldfrag(vbuf + (aKV ^ 64) + sl * 2048);
            o[0][sl] = mfma16(va, pb[0][0], o[0][sl]);
            o[0][sl] = mfma16(vx, pb[0][1], o[0][sl]);
            o[1][sl] = mfma16(va, pb[1][0], o[1][sl]);
            o[1][sl] = mfma16(vx, pb[1][1], o[1][sl]);
        }
        __builtin_amdgcn_s_setprio(0);
        par ^= 1;
    }

    // ---- epilogue: o[g][sl][r] = O[q=q0+g*64+l16][d=sl*16+quad*4+r] --------
#pragma unroll
    for (int g = 0; g < 2; ++g) {
        float rinv = 1.0f / lacc[g][0];     // row-sum, uniform across quads
        int q = q0 + g * 64 + l16;
        unsigned short* op = Ab + (((size_t)(n * SEQ + q)) * HEADS + h) * HD + qsh;
#pragma unroll
        for (int sl = 0; sl < 4; ++sl) {
            u16x4 u;
            u[0] = f2bf(o[g][sl][0] * rinv);
            u[1] = f2bf(o[g][sl][1] * rinv);
            u[2] = f2bf(o[g][sl][2] * rinv);
            u[3] = f2bf(o[g][sl][3] * rinv);
            *(u16x4*)(op + sl * 16) = u;
        }
    }
}

// ---------------- kernel: out = Ab @ Wo^T + bo -----------------------------
// v3: 128x64 tiles, A+B double-buffered (48 KB), ONE barrier per K-step,
// XCD-affinity block remap (xcd owns rt group for all ct -> L2-resident).
__global__ __launch_bounds__(256) void out_gemm_kernel(
    const unsigned short* __restrict__ Ab, const unsigned short* __restrict__ Wob,
    const float* __restrict__ bo, float* __restrict__ out)
{
    // A par0 @0 (16K), A par1 @16384, B par0 @32768 (8K), B par1 @40960
    __shared__ __align__(16) char lds[49152];

    int tid = threadIdx.x;
    int wave = tid >> 6, lane = tid & 63;
    int quad = lane >> 4, l16 = lane & 15;
    int bidx = blockIdx.x;
    int xcdg = bidx & 7;
    int jg   = bidx >> 3;                 // 0..63
    int rt = xcdg * 4 + (jg & 3);
    int ct = jg >> 2;
    int wr = wave >> 1, wc = wave & 1;

    int srow = lane >> 3, sslot = lane & 7;
    int stoff = srow * 2048 + (((sslot - srow) & 7) * 16);
    const char* gA = (const char*)Ab  + (size_t)rt * 128 * 2048 + stoff;
    const char* gB = (const char*)Wob + (size_t)ct * 64 * 2048 + stoff;

    int aA[4], aB[2];    // in-tile offsets, NO base
#pragma unroll
    for (int i = 0; i < 4; ++i) {
        int rowA = wr * 64 + i * 16 + l16;
        aA[i] = rowA * 128 + (((quad + rowA) & 7) * 16);
    }
#pragma unroll
    for (int sl = 0; sl < 2; ++sl) {
        int rowB = wc * 32 + sl * 16 + l16;
        aB[sl] = rowB * 128 + (((quad + rowB) & 7) * 16);
    }

    // ---- prologue: stage f=0 into parity 0 ---------------------------------
#pragma unroll
    for (int i = 0; i < 4; ++i) {
        int c = wave * 4 + i;                      // A: 16 chunks of 8 rows
        GLOAD_LDS(gA + (size_t)c * 16384, lds + c * 1024);
    }
#pragma unroll
    for (int i = 0; i < 2; ++i) {
        int c = wave * 2 + i;                      // B: 8 chunks
        GLOAD_LDS(gB + (size_t)c * 16384, lds + 32768 + c * 1024);
    }

    f32x4 acc[4][2] = {};
    int par = 0;
    for (int f = 0; f < ED; f += 64) {
        int fn = (f + 64) & (ED - 1);              // wrapped (harmless at end)
        __syncthreads();   // tiles(par) visible; prefetches have full-iter lead
        // ---- prefetch next K-slab into parity^1 ----------------------------
        {
            int pA = (par ^ 1) * 16384;
            int pB = 32768 + (par ^ 1) * 8192;
#pragma unroll
            for (int i = 0; i < 4; ++i) {
                int c = wave * 4 + i;
                GLOAD_LDS(gA + (size_t)c * 16384 + fn * 2, lds + pA + c * 1024);
            }
#pragma unroll
            for (int i = 0; i < 2; ++i) {
                int c = wave * 2 + i;
                GLOAD_LDS(gB + (size_t)c * 16384 + fn * 2, lds + pB + c * 1024);
            }
        }
        int bA = par * 16384;
        int bB = 32768 + par * 8192;
#pragma unroll
        for (int kk = 0; kk < 2; ++kk) {
            int x = kk * 64;
            bf16x8 af[4], bfr[2];
#pragma unroll
            for (int i = 0; i < 4; ++i)    af[i]  = ldfrag(lds + bA + (aA[i] ^ x));
#pragma unroll
            for (int sl = 0; sl < 2; ++sl) bfr[sl] = ldfrag(lds + bB + (aB[sl] ^ x));
#pragma unroll
            for (int i = 0; i < 4; ++i)
#pragma unroll
                for (int sl = 0; sl < 2; ++sl)
                    acc[i][sl] = mfma16(af[i], bfr[sl], acc[i][sl]);
        }
        par ^= 1;
    }

    float bv[2];
#pragma unroll
    for (int sl = 0; sl < 2; ++sl)
        bv[sl] = bo[ct * 64 + wc * 32 + sl * 16 + l16];
#pragma unroll
    for (int i = 0; i < 4; ++i)
#pragma unroll
        for (int r = 0; r < 4; ++r) {
            int row = rt * 128 + wr * 64 + i * 16 + quad * 4 + r;
#pragma unroll
            for (int sl = 0; sl < 2; ++sl) {
                int e = ct * 64 + wc * 32 + sl * 16 + l16;
                out[(size_t)row * ED + e] = acc[i][sl][r] + bv[sl];
            }
        }
}

// ---------------- launcher -------------------------------------------------
extern "C" void kernel_launch(void* const* d_in, const int* in_sizes, int n_in,
                              void* d_out, int out_size, void* d_ws, size_t ws_size,
                              hipStream_t stream)
{
    const float* values = (const float*)d_in[0];
    const float* keys   = (const float*)d_in[1];
    const float* query  = (const float*)d_in[2];
    const int*   mask   = (const int*)d_in[3];
    const float* Wv     = (const float*)d_in[4];
    const float* Wk     = (const float*)d_in[5];
    const float* Wq     = (const float*)d_in[6];
    const float* Wo     = (const float*)d_in[7];
    const float* bo     = (const float*)d_in[8];
    float* out = (float*)d_out;

    char* w = (char*)d_ws;
    unsigned short* Qb  = (unsigned short*)(w);              //  8 MB
    unsigned short* Kb  = (unsigned short*)(w +  8388608);   //  8 MB
    unsigned short* Vt  = (unsigned short*)(w + 16777216);   //  8 MB tiled V
    unsigned short* Ab  = (unsigned short*)(w + 25165824);   //  8 MB
    unsigned long long* Mb = (unsigned long long*)(w + 33554432); // 1 MB
    unsigned short* Wob = (unsigned short*)(w + 34603008);   //  2 MB

    proj_prep_kernel<<<3072 + 2048 + 1024, 256, 0, stream>>>(
        query, keys, values, Wq, Wk, Wv, Qb, Kb, Vt, mask, Mb, Wo, Wob);
    attn_kernel<<<512, 256, 0, stream>>>(Qb, Kb, Vt, Mb, Ab);
    out_gemm_kernel<<<512, 256, 0, stream>>>(Ab, Wob, bo, out);
}

// Round 13
// 228.168 us; speedup vs baseline: 1.0141x; 1.0139x over previous
//
#include <hip/hip_runtime.h>
#include <hip/hip_bf16.h>

// Problem constants
#define NB 2
#define SEQ 2048
#define HEADS 16
#define HD 64
#define ED 1024

typedef __bf16 bf16x8 __attribute__((ext_vector_type(8)));
typedef float f32x4 __attribute__((ext_vector_type(4)));
typedef unsigned short u16x8 __attribute__((ext_vector_type(8)));
typedef unsigned short u16x4 __attribute__((ext_vector_type(4)));

#if __has_builtin(__builtin_amdgcn_exp2f)
#define EXP2(x) __builtin_amdgcn_exp2f(x)   // raw v_exp_f32 (no denorm guard seq)
#else
#define EXP2(x) __builtin_exp2f(x)
#endif

__device__ __forceinline__ unsigned short f2bf(float f) {
    unsigned u = __builtin_bit_cast(unsigned, f);
    u += 0x7fffu + ((u >> 16) & 1u);   // RNE
    return (unsigned short)(u >> 16);
}

__device__ __forceinline__ bf16x8 cvt8(const float* __restrict__ p) {
    const float4* p4 = (const float4*)p;
    float4 a = p4[0], b = p4[1];
    u16x8 u;
    u[0] = f2bf(a.x); u[1] = f2bf(a.y); u[2] = f2bf(a.z); u[3] = f2bf(a.w);
    u[4] = f2bf(b.x); u[5] = f2bf(b.y); u[6] = f2bf(b.z); u[7] = f2bf(b.w);
    return __builtin_bit_cast(bf16x8, u);
}

__device__ __forceinline__ bf16x8 ldfrag(const void* p) {
    uint4 v = *(const uint4*)p;
    return __builtin_bit_cast(bf16x8, v);
}

__device__ __forceinline__ f32x4 mfma16(bf16x8 a, bf16x8 b, f32x4 c) {
    return __builtin_amdgcn_mfma_f32_16x16x32_bf16(a, b, c, 0, 0, 0);
}

// pack two f32 into a bf16 pair in ONE VALU op (v_cvt_pk_bf16_f32, RNE):
// D[15:0] = bf16(S0) = lo, D[31:16] = bf16(S1) = hi -- standard AMD pk
// ordering (matches v_cvt_pkrtz_f16_f32 / llvm.amdgcn.cvt.pk.bf16.f32).
// r10 established r9's failure was the V-stride bug, NOT this op (identical
// absmax under both packers); this is its first test on a correct baseline.
__device__ __forceinline__ unsigned cvtpk(float lo, float hi) {
    unsigned d;
    asm("v_cvt_pk_bf16_f32 %0, %1, %2" : "=v"(d) : "v"(lo), "v"(hi));
    return d;
}

#define GLOAD_LDS(gp, lp) \
    __builtin_amdgcn_global_load_lds( \
        (const __attribute__((address_space(1))) unsigned int*)(gp), \
        (__attribute__((address_space(3))) unsigned int*)(lp), 16, 0, 0)

// softmax scale folded into Q at projection: (1/sqrt(1024)) * log2(e)
#define QSCALE 0.04508422f

// ---------------- kernel: QKV projections + mask->bits + Wo->bf16 ----------
// v5 grid: 0..3071 proj (heavy). 3072..5119 mask bit-pack (fat blocks,
// 4096 ints each). 5120..6143 Wo convert. Total 6144 WGs.
// Q,K stored [n][h][s][64] bf16 (Q pre-scaled by QSCALE);
// V stored tiled [n][h][s/64][d][64] bf16.
__global__ __launch_bounds__(256) void proj_prep_kernel(
    const float* __restrict__ qin, const float* __restrict__ kin, const float* __restrict__ vin,
    const float* __restrict__ Wq, const float* __restrict__ Wk, const float* __restrict__ Wv,
    unsigned short* __restrict__ Qb, unsigned short* __restrict__ Kb,
    unsigned short* __restrict__ Vt,
    const int* __restrict__ mask, unsigned long long* __restrict__ bits,
    const float* __restrict__ Wo, unsigned short* __restrict__ Wob)
{
    __shared__ __align__(16) char tile[64 * 144];   // 64 rows x 144B (128B data + pad)

    int bid = blockIdx.x;
    if (bid >= 3072) {
        int b2 = bid - 3072;
        if (b2 < 2048) {
            // mask bit-pack: 4096 ints per block, 1024 per wave, 16 ballots
            int lane = threadIdx.x & 63;
            size_t base = (size_t)b2 * 4096 + (size_t)(threadIdx.x >> 6) * 1024;
#pragma unroll
            for (int j = 0; j < 16; ++j) {
                size_t i = base + (size_t)j * 64 + lane;
                unsigned long long bb = __ballot(mask[i] != 0);
                if (lane == 0) bits[i >> 6] = bb;
            }
        } else {
            size_t i = ((size_t)(b2 - 2048) * 256 + threadIdx.x) * 4;
            float4 v = *(const float4*)(Wo + i);
            u16x4 u;
            u[0] = f2bf(v.x); u[1] = f2bf(v.y); u[2] = f2bf(v.z); u[3] = f2bf(v.w);
            *(u16x4*)(Wob + i) = u;
        }
        return;
    }

    int t3  = bid >> 10;
    int rem = bid & 1023;
    int h   = rem >> 6;
    int rt  = rem & 63;
    int wave = threadIdx.x >> 6, lane = threadIdx.x & 63;
    int quad = lane >> 4, l16 = lane & 15;

    const float* in = (t3 == 0) ? qin : ((t3 == 1) ? kin : vin);
    const float* W  = (t3 == 0) ? Wq  : ((t3 == 1) ? Wk  : Wv);

    int r0 = rt * 64 + wave * 16;   // global token row base for this wave

    bf16x8 bf0[4], bf1[4];
#pragma unroll
    for (int sl = 0; sl < 4; ++sl) {
        const float* wrow = W + (sl * 16 + l16) * 64;
        bf0[sl] = cvt8(wrow + quad * 8);
        bf1[sl] = cvt8(wrow + 32 + quad * 8);
    }
    const float* xrow = in + (size_t)(r0 + l16) * ED + h * 64;
    bf16x8 af0 = cvt8(xrow + quad * 8);
    bf16x8 af1 = cvt8(xrow + 32 + quad * 8);

    f32x4 acc[4];
#pragma unroll
    for (int sl = 0; sl < 4; ++sl) {
        f32x4 c = {0.f, 0.f, 0.f, 0.f};
        c = mfma16(af0, bf0[sl], c);
        c = mfma16(af1, bf1[sl], c);
        acc[sl] = c;
    }
    float sc = (t3 == 0) ? QSCALE : 1.0f;

    size_t nh = (size_t)((r0 >> 11) * HEADS + h);   // 64-row tile never straddles n
    int rl = lane >> 3, cl = lane & 7;              // readback row-in-group / 16B slot

    if (t3 != 2) {
        // ---- Q/K: LDS tile [s_local][e], wave-private rows, no barrier -----
#pragma unroll
        for (int r = 0; r < 4; ++r) {
            int srow = wave * 16 + quad * 4 + r;
#pragma unroll
            for (int sl = 0; sl < 4; ++sl)
                *(unsigned short*)(tile + srow * 144 + (sl * 16 + l16) * 2) =
                    f2bf(acc[sl][r] * sc);
        }
        unsigned short* dst = (t3 == 0) ? Qb : Kb;
        int s0 = (r0 & 2047);                        // this wave's first token row
#pragma unroll
        for (int g = 0; g < 2; ++g) {
            int lrow = wave * 16 + g * 8 + rl;
            uint4 v = *(const uint4*)(tile + lrow * 144 + cl * 16);
            *(uint4*)(dst + (nh * SEQ + (s0 & ~15) + g * 8 + rl) * HD + cl * 8) = v;
        }
    } else {
        // ---- V: LDS tile [e][s_local] (transpose), barrier across waves ----
#pragma unroll
        for (int r = 0; r < 4; ++r) {
            int srow = wave * 16 + quad * 4 + r;
#pragma unroll
            for (int sl = 0; sl < 4; ++sl)
                *(unsigned short*)(tile + (sl * 16 + l16) * 144 + srow * 2) =
                    f2bf(acc[sl][r]);
        }
        __syncthreads();
        int s_tile = rt & 31;
#pragma unroll
        for (int g = 0; g < 2; ++g) {
            int erow = wave * 16 + g * 8 + rl;
            uint4 v = *(const uint4*)(tile + erow * 144 + cl * 16);
            *(uint4*)(Vt + ((nh * 32 + s_tile) * 64 + erow) * 64 + cl * 8) = v;
        }
    }
}

// ---------------- kernel: flash attention, full-K, no split ----------------
// v13 = v12 (passing, attn 67.6us: v4 schedule + s_setprio on both MFMA
// clusters) + cvt_pk packer (1 op vs packbf's 3; 16x/wave-iter on the
// dominant VALU pipe, 42.5% busy). Single-variable change; cvt_pk's only
// prior failure (r9) was fully attributed to the V-stride bug by r10's
// identical-absmax control.
// Structure (v4/v11): each wave does TWO 16-q blocks (shared K/V frags);
// 128 q/block, grid 512 = 2 blocks/CU, 8 waves/CU. K AND V double-buffered,
// ONE barrier per K-tile, both prefetches right after it.
// LDS: K dbuf 16K + V dbuf 16K + P 4x4K = 49152 B.
__global__ __launch_bounds__(256, 2) void attn_kernel(
    const unsigned short* __restrict__ Qb, const unsigned short* __restrict__ Kb,
    const unsigned short* __restrict__ Vt2, const unsigned long long* __restrict__ mb,
    unsigned short* __restrict__ Ab)
{
    // K par0 @0, K par1 @8192, V par0 @16384, V par1 @24576,
    // P @32768 + wave*4096 + g*2048
    __shared__ __align__(16) char smem[32768 + 4 * 4096];

    int tid = threadIdx.x;
    int wave = tid >> 6, lane = tid & 63;
    int quad = lane >> 4, l16 = lane & 15;

    // XCD swizzle: 4 consecutive nh per XCD -> K/V resident in its L2
    int b   = blockIdx.x;
    int xcd = b & 7;
    int j   = b >> 3;             // 0..63
    int nh  = xcd * 4 + (j >> 4);
    int qb  = j & 15;
    int n = nh >> 4, h = nh & 15;
    int q0 = qb * 128 + wave * 16;          // q-block 0; q-block 1 at +64

    size_t headoff = (size_t)nh * SEQ * HD;
    // Q fragments (B-operand), two q-blocks
    bf16x8 qf[2][2];
#pragma unroll
    for (int g = 0; g < 2; ++g) {
        const unsigned short* qrow = Qb + headoff + (size_t)(q0 + g * 64 + l16) * HD;
        qf[g][0] = ldfrag(qrow + quad * 8);
        qf[g][1] = ldfrag(qrow + 32 + quad * 8);
    }

    // staging: per-lane source offset (bytes) with rotation ((slot - row)&7)
    int srow = lane >> 3, sslot = lane & 7;
    int stoff = srow * 128 + (((sslot - srow) & 7) * 16);

    // ds read address registers (bytes, loop-invariant; par base added in loop)
    int rotA = ((quad + l16) & 7) * 16;
    int aKV = l16 * 128 + rotA;            // + kt/sl*2048 ; ^64 high half

    // P tiles: per wave 2 x (16 rows x 128B), XOR swizzle bits 4-6 by (l16&7)
    int pswz = (l16 & 7) << 4;
    char* prow0 = smem + 32768 + wave * 4096 + l16 * 128;
    char* prow1 = prow0 + 2048;
    int pwoff = (quad * 8) ^ pswz;         // write: prowG + (pwoff ^ kt*32)
    int proff = (quad * 16) ^ pswz;        // read:  pb0 @ prowG+proff; pb1 @ ^64

    const unsigned short* gK = Kb + headoff;
    // V base kept as ELEMENT pointer (unsigned short*): one tile = 4096
    // elements = 8192 bytes (r10 root cause -- keep element arithmetic).
    const unsigned short* gV = Vt2 + (size_t)nh * (32 * 4096);
    const unsigned long long* mbase = mb + (size_t)n * (SEQ * SEQ / 64)
                                         + (size_t)(q0 + l16) * (SEQ / 64);
    // q-block 1 mask rows at +64*(SEQ/64) = +2048 elements

    // all-ones bf16 A-fragment for row sums
    u16x8 ou;
#pragma unroll
    for (int jj = 0; jj < 8; ++jj) ou[jj] = 0x3F80;
    bf16x8 ones = __builtin_bit_cast(bf16x8, ou);

    f32x4 o[2][4] = {};
    f32x4 lacc[2] = {{0,0,0,0},{0,0,0,0}};
    int qsh = quad * 4;

    // ---- prologue: stage K_0, V_0 -> parity 0 ------------------------------
    {
        const char* sK = (const char*)gK + stoff;
        const char* sV = (const char*)gV + stoff;
#pragma unroll
        for (int i2 = 0; i2 < 2; ++i2) {
            int c = wave * 2 + i2;
            GLOAD_LDS(sK + c * 1024, smem + c * 1024);
            GLOAD_LDS(sV + c * 1024, smem + 16384 + c * 1024);
        }
    }
    unsigned long long mnext0 = mbase[0] >> qsh;
    unsigned long long mnext1 = mbase[2048] >> qsh;

    int par = 0;
    for (int kb = 0; kb < SEQ; kb += 64) {
        int kbn = (kb + 64) & (SEQ - 1);   // wrapped next tile (harmless at end)
        // ONE barrier: K_i/V_i visible; last iter's prefetches (full-iter
        // lead) drained by the syncthreads-implied s_waitcnt vmcnt(0)
        __syncthreads();
        // ---- prefetch K_{i+1}, V_{i+1} into parity^1 -----------------------
        {
            const char* sK = (const char*)(gK + (size_t)kbn * 64) + stoff;
            // ELEMENT arithmetic on ushort*: (kbn>>6)*4096 elems = 8192 B/tile
            const char* sV = (const char*)(gV + (size_t)(kbn >> 6) * 4096) + stoff;
            char* dK = smem + (par ^ 1) * 8192;
            char* dV = smem + 16384 + (par ^ 1) * 8192;
#pragma unroll
            for (int i2 = 0; i2 < 2; ++i2) {
                int c = wave * 2 + i2;
                GLOAD_LDS(sK + c * 1024, dK + c * 1024);
                GLOAD_LDS(sV + c * 1024, dV + c * 1024);
            }
        }
        // mask rows for this lane's queries: registered one iteration ahead
        unsigned long long m64_0 = mnext0, m64_1 = mnext1;
        mnext0 = mbase[kbn >> 6] >> qsh;
        mnext1 = mbase[2048 + (kbn >> 6)] >> qsh;

        // ---- K fragments (A-operand) from current buffer, shared by both g -
        const char* kbuf = smem + par * 8192;
        bf16x8 kf[4][2];
#pragma unroll
        for (int kt = 0; kt < 4; ++kt) {
            kf[kt][0] = ldfrag(kbuf + aKV + kt * 2048);
            kf[kt][1] = ldfrag(kbuf + (aKV ^ 64) + kt * 2048);
        }
        // ---- per q-block: S^T = K*Q^T ; mask+exp ; P write -----------------
#pragma unroll
        for (int g = 0; g < 2; ++g) {
            unsigned long long m64 = g ? m64_1 : m64_0;
            char* prow = g ? prow1 : prow0;
            f32x4 c[4];
            __builtin_amdgcn_s_setprio(1);   // QK MFMA cluster (T5)
#pragma unroll
            for (int kt = 0; kt < 4; ++kt) {
                f32x4 cc = {0.f, 0.f, 0.f, 0.f};
                cc = mfma16(kf[kt][0], qf[g][0], cc);
                cc = mfma16(kf[kt][1], qf[g][1], cc);
                c[kt] = cc;   // c[kt][r]: key = kb+kt*16+quad*4+r, q = q0+g*64+l16
            }
            __builtin_amdgcn_s_setprio(0);
            unsigned mlo = (unsigned)m64;
            unsigned mhi = (unsigned)(m64 >> 32);
#pragma unroll
            for (int kt = 0; kt < 4; ++kt) {
                unsigned mw = (kt & 2) ? mhi : mlo;
                int bs = (kt & 1) ? 16 : 0;
                float p0 = ((mw >> (bs + 0)) & 1u) ? EXP2(c[kt][0]) : 0.f;
                float p1 = ((mw >> (bs + 1)) & 1u) ? EXP2(c[kt][1]) : 0.f;
                float p2 = ((mw >> (bs + 2)) & 1u) ? EXP2(c[kt][2]) : 0.f;
                float p3 = ((mw >> (bs + 3)) & 1u) ? EXP2(c[kt][3]) : 0.f;
                uint2 dw = { cvtpk(p0, p1), cvtpk(p2, p3) };
                *(uint2*)(prow + (pwoff ^ (kt * 32))) = dw;
            }
        }
        // ---- P^T B-fragments (in-wave write->read ordering via DS pipe) ----
        bf16x8 pb[2][2];
        pb[0][0] = ldfrag(prow0 + proff);
        pb[0][1] = ldfrag(prow0 + (proff ^ 64));
        pb[1][0] = ldfrag(prow1 + proff);
        pb[1][1] = ldfrag(prow1 + (proff ^ 64));
        // rowsum + PV MFMA cluster (T5)
        __builtin_amdgcn_s_setprio(1);
        // row sums on the matrix pipe (quad-uniform result)
        lacc[0] = mfma16(ones, pb[0][0], lacc[0]);
        lacc[0] = mfma16(ones, pb[0][1], lacc[0]);
        lacc[1] = mfma16(ones, pb[1][0], lacc[1]);
        lacc[1] = mfma16(ones, pb[1][1], lacc[1]);
        // ---- O^T = V^T * P^T : V fragment read ONCE, used for both g -------
        const char* vbuf = smem + 16384 + par * 8192;
#pragma unroll
        for (int sl = 0; sl < 4; ++sl) {
            bf16x8 va = ldfrag(vbuf + aKV + sl * 2048);
            bf16x8 vx = ldfrag(vbuf + (aKV ^ 64) + sl * 2048);
            o[0][sl] = mfma16(va, pb[0][0], o[0][sl]);
            o[0][sl] = mfma16(vx, pb[0][1], o[0][sl]);
            o[1][sl] = mfma16(va, pb[1][0], o[1][sl]);
            o[1][sl] = mfma16(vx, pb[1][1], o[1][sl]);
        }
        __builtin_amdgcn_s_setprio(0);
        par ^= 1;
    }

    // ---- epilogue: o[g][sl][r] = O[q=q0+g*64+l16][d=sl*16+quad*4+r] --------
#pragma unroll
    for (int g = 0; g < 2; ++g) {
        float rinv = 1.0f / lacc[g][0];     // row-sum, uniform across quads
        int q = q0 + g * 64 + l16;
        unsigned short* op = Ab + (((size_t)(n * SEQ + q)) * HEADS + h) * HD + qsh;
#pragma unroll
        for (int sl = 0; sl < 4; ++sl) {
            u16x4 u;
            u[0] = f2bf(o[g][sl][0] * rinv);
            u[1] = f2bf(o[g][sl][1] * rinv);
            u[2] = f2bf(o[g][sl][2] * rinv);
            u[3] = f2bf(o[g][sl][3] * rinv);
            *(u16x4*)(op + sl * 16) = u;
        }
    }
}

// ---------------- kernel: out = Ab @ Wo^T + bo -----------------------------
// v3: 128x64 tiles, A+B double-buffered (48 KB), ONE barrier per K-step,
// XCD-affinity block remap (xcd owns rt group for all ct -> L2-resident).
__global__ __launch_bounds__(256) void out_gemm_kernel(
    const unsigned short* __restrict__ Ab, const unsigned short* __restrict__ Wob,
    const float* __restrict__ bo, float* __restrict__ out)
{
    // A par0 @0 (16K), A par1 @16384, B par0 @32768 (8K), B par1 @40960
    __shared__ __align__(16) char lds[49152];

    int tid = threadIdx.x;
    int wave = tid >> 6, lane = tid & 63;
    int quad = lane >> 4, l16 = lane & 15;
    int bidx = blockIdx.x;
    int xcdg = bidx & 7;
    int jg   = bidx >> 3;                 // 0..63
    int rt = xcdg * 4 + (jg & 3);
    int ct = jg >> 2;
    int wr = wave >> 1, wc = wave & 1;

    int srow = lane >> 3, sslot = lane & 7;
    int stoff = srow * 2048 + (((sslot - srow) & 7) * 16);
    const char* gA = (const char*)Ab  + (size_t)rt * 128 * 2048 + stoff;
    const char* gB = (const char*)Wob + (size_t)ct * 64 * 2048 + stoff;

    int aA[4], aB[2];    // in-tile offsets, NO base
#pragma unroll
    for (int i = 0; i < 4; ++i) {
        int rowA = wr * 64 + i * 16 + l16;
        aA[i] = rowA * 128 + (((quad + rowA) & 7) * 16);
    }
#pragma unroll
    for (int sl = 0; sl < 2; ++sl) {
        int rowB = wc * 32 + sl * 16 + l16;
        aB[sl] = rowB * 128 + (((quad + rowB) & 7) * 16);
    }

    // ---- prologue: stage f=0 into parity 0 ---------------------------------
#pragma unroll
    for (int i = 0; i < 4; ++i) {
        int c = wave * 4 + i;                      // A: 16 chunks of 8 rows
        GLOAD_LDS(gA + (size_t)c * 16384, lds + c * 1024);
    }
#pragma unroll
    for (int i = 0; i < 2; ++i) {
        int c = wave * 2 + i;                      // B: 8 chunks
        GLOAD_LDS(gB + (size_t)c * 16384, lds + 32768 + c * 1024);
    }

    f32x4 acc[4][2] = {};
    int par = 0;
    for (int f = 0; f < ED; f += 64) {
        int fn = (f + 64) & (ED - 1);              // wrapped (harmless at end)
        __syncthreads();   // tiles(par) visible; prefetches have full-iter lead
        // ---- prefetch next K-slab into parity^1 ----------------------------
        {
            int pA = (par ^ 1) * 16384;
            int pB = 32768 + (par ^ 1) * 8192;
#pragma unroll
            for (int i = 0; i < 4; ++i) {
                int c = wave * 4 + i;
                GLOAD_LDS(gA + (size_t)c * 16384 + fn * 2, lds + pA + c * 1024);
            }
#pragma unroll
            for (int i = 0; i < 2; ++i) {
                int c = wave * 2 + i;
                GLOAD_LDS(gB + (size_t)c * 16384 + fn * 2, lds + pB + c * 1024);
            }
        }
        int bA = par * 16384;
        int bB = 32768 + par * 8192;
#pragma unroll
        for (int kk = 0; kk < 2; ++kk) {
            int x = kk * 64;
            bf16x8 af[4], bfr[2];
#pragma unroll
            for (int i = 0; i < 4; ++i)    af[i]  = ldfrag(lds + bA + (aA[i] ^ x));
#pragma unroll
            for (int sl = 0; sl < 2; ++sl) bfr[sl] = ldfrag(lds + bB + (aB[sl] ^ x));
#pragma unroll
            for (int i = 0; i < 4; ++i)
#pragma unroll
                for (int sl = 0; sl < 2; ++sl)
                    acc[i][sl] = mfma16(af[i], bfr[sl], acc[i][sl]);
        }
        par ^= 1;
    }

    float bv[2];
#pragma unroll
    for (int sl = 0; sl < 2; ++sl)
        bv[sl] = bo[ct * 64 + wc * 32 + sl * 16 + l16];
#pragma unroll
    for (int i = 0; i < 4; ++i)
#pragma unroll
        for (int r = 0; r < 4; ++r) {
            int row = rt * 128 + wr * 64 + i * 16 + quad * 4 + r;
#pragma unroll
            for (int sl = 0; sl < 2; ++sl) {
                int e = ct * 64 + wc * 32 + sl * 16 + l16;
                out[(size_t)row * ED + e] = acc[i][sl][r] + bv[sl];
            }
        }
}

// ---------------- launcher -------------------------------------------------
extern "C" void kernel_launch(void* const* d_in, const int* in_sizes, int n_in,
                              void* d_out, int out_size, void* d_ws, size_t ws_size,
                              hipStream_t stream)
{
    const float* values = (const float*)d_in[0];
    const float* keys   = (const float*)d_in[1];
    const float* query  = (const float*)d_in[2];
    const int*   mask   = (const int*)d_in[3];
    const float* Wv     = (const float*)d_in[4];
    const float* Wk     = (const float*)d_in[5];
    const float* Wq     = (const float*)d_in[6];
    const float* Wo     = (const float*)d_in[7];
    const float* bo     = (const float*)d_in[8];
    float* out = (float*)d_out;

    char* w = (char*)d_ws;
    unsigned short* Qb  = (unsigned short*)(w);              //  8 MB
    unsigned short* Kb  = (unsigned short*)(w +  8388608);   //  8 MB
    unsigned short* Vt  = (unsigned short*)(w + 16777216);   //  8 MB tiled V
    unsigned short* Ab  = (unsigned short*)(w + 25165824);   //  8 MB
    unsigned long long* Mb = (unsigned long long*)(w + 33554432); // 1 MB
    unsigned short* Wob = (unsigned short*)(w + 34603008);   //  2 MB

    proj_prep_kernel<<<3072 + 2048 + 1024, 256, 0, stream>>>(
        query, keys, values, Wq, Wk, Wv, Qb, Kb, Vt, mask, Mb, Wo, Wob);
    attn_kernel<<<512, 256, 0, stream>>>(Qb, Kb, Vt, Mb, Ab);
    out_gemm_kernel<<<512, 256, 0, stream>>>(Ab, Wob, bo, out);
}